// Round 11
// baseline (83.951 us; speedup 1.0000x reference)
//
#include <hip/hip_runtime.h>

// out[b,co,h,w] = sum_ci dq( conv3x3(x[b,ci], W[ci,co]) + b[ci,co] )
// Bit-exactness contract (verified R3 absmax==0, R4/R6/R7/R9/R10 = 1.43e-6):
//   per-pixel conv = sequential fma over k=(kh*3+kw) ascending, seeded from 0;
//   bias after as plain f32 add; t = y * (float)(15/9); rintf (half-even);
//   dequant+sum: fma(q, 0.6f, acc), ci ascending. v_pk_fma_f32 is IEEE per
//   32-bit half -> identical bits per pixel.
// R11: attack the two remaining stalls (R10 kernel ~28us vs ~6us overlapped
// pipe floors):
//  (a) staging: threads 0..199 own one (r,c) slot of the 10x20 halo, bounds
//      computed ONCE; 16 INDEPENDENT unrolled global_load_dword (ci-strided,
//      safe-address + cndmask for OOB) then 16 ds_write_b32 with static
//      offsets -> 16 loads in flight vs ~1 in the old idx-loop.
//  (b) tail: grid 1568 (co-split x2, COG=4) = 6.1 blocks/CU vs 3.06 (25%
//      straggler tail at 784). Also halves per-ci SMEM batch (40 dwords).

typedef float v2f __attribute__((ext_vector_type(2)));

constexpr int B_    = 8;
constexpr int CIN   = 16;
constexpr int COUT  = 32;
constexpr int H_    = 112;
constexpr int W_    = 112;
constexpr int TW    = 16;            // tile width  (112 = 7*16)
constexpr int TH    = 8;             // tile height (112 = 14*8)
constexpr int LDSW  = 20;            // halo row: cols map gw = tile_x-1+c
constexpr int HH_   = TH + 2;        // halo rows 10
constexpr int COG   = 4;             // co per wave

__global__ __launch_bounds__(256, 4)
void conv_quant_sum_kernel(const float* __restrict__ x,
                           const float* __restrict__ w,
                           const float* __restrict__ bias,
                           float* __restrict__ out)
{
#pragma clang fp contract(off)
    const float QS = (float)(15.0 / 9.0);   // 1.66666663f
    const float DQ = 0.6f;                  // post-round dequant multiplier

    __shared__ float xs[CIN][HH_][LDSW];    // 16*10*20*4 = 12.8 KB

    const int t    = threadIdx.x;
    const int lane = t & 63;
    const int tx   = lane & 7;              // pair col: pixels 2tx, 2tx+1
    const int ty   = lane >> 3;             // row 0..7
    const int wid  = __builtin_amdgcn_readfirstlane(t >> 6);

    const int tile_x = blockIdx.x * TW;
    const int tile_y = blockIdx.y * TH;
    const int b      = blockIdx.z >> 1;
    const int cog    = (blockIdx.z & 1) * 16 + wid * COG;   // 0..28 step 4

    // ---- stage x halo (10 rows x 20 cols per ci), latency-batched ----
    // thread t<200 owns slot (sr,sc); 16 independent ci-strided loads.
    const float* xb = x + (size_t)b * CIN * H_ * W_;
    {
        const int sr = t / 20;              // one magic-divide, once
        const int sc = t - sr * 20;
        const bool active = (sr < HH_);     // t < 200
        const int gh = tile_y + sr - 1;
        const int gw = tile_x + sc - 1;
        const bool inb = active && ((unsigned)gh < (unsigned)H_) &&
                         ((unsigned)gw < (unsigned)W_);
        const float* sp = inb ? (xb + gh * W_ + gw) : xb;   // safe address
        float v[CIN];
#pragma unroll
        for (int ci = 0; ci < CIN; ++ci)    // 16 independent loads in flight
            v[ci] = sp[ci * (H_ * W_)];
#pragma unroll
        for (int ci = 0; ci < CIN; ++ci)
            v[ci] = inb ? v[ci] : 0.0f;
        if (active) {
#pragma unroll
            for (int ci = 0; ci < CIN; ++ci)  // static LDS offsets (ci*800B)
                xs[ci][sr][sc] = v[ci];
        }
    }
    __syncthreads();

    v2f acc[COG];
#pragma unroll
    for (int co = 0; co < COG; ++co) acc[co] = v2f{0.0f, 0.0f};

    for (int ci = 0; ci < CIN; ++ci) {
        // windows for pixel pair (gw = tile_x+2tx, +1): LDS cols 2tx..2tx+3
        // (col c <-> gw = tile_x-1+c) -> two even-word-aligned b64 per row
        v2f xw[3][3];
#pragma unroll
        for (int r = 0; r < 3; ++r) {
            const float* row = &xs[ci][ty + r][2 * tx];
            v2f p0 = *reinterpret_cast<const v2f*>(row);      // cols 2tx,2tx+1
            v2f p1 = *reinterpret_cast<const v2f*>(row + 2);  // cols 2tx+2,+3
            xw[r][0] = p0;
            xw[r][1] = v2f{p0.y, p1.x};
            xw[r][2] = p1;
        }

        const float* wc = w + (ci * COUT + cog) * 9;   // wave-uniform scalar
        const float* bc = bias + ci * COUT + cog;
#pragma unroll
        for (int co = 0; co < COG; ++co) {
            v2f s = v2f{0.0f, 0.0f};                   // conv seeded from 0
#pragma unroll
            for (int k = 0; k < 9; ++k) {
                float wv = wc[co * 9 + k];
                s = __builtin_elementwise_fma(xw[k / 3][k % 3], v2f{wv, wv}, s);
            }
            float bv = bc[co];
            v2f y  = s + v2f{bv, bv};                  // bias: pk_add
            v2f tq = y * v2f{QS, QS};                  // pk_mul
            v2f q;
            q.x = rintf(tq.x);                         // v_rndne_f32 half-even
            q.y = rintf(tq.y);
            acc[co] = __builtin_elementwise_fma(q, v2f{DQ, DQ}, acc[co]);
        }
    }

    // ---- store: 2 adjacent pixels -> 8B-aligned dwordx2 ----
    float* ob = out + ((size_t)b * COUT + cog) * H_ * W_;
    const int oh = tile_y + ty;
    const int ow = tile_x + 2 * tx;
#pragma unroll
    for (int co = 0; co < COG; ++co)
        *reinterpret_cast<v2f*>(ob + co * H_ * W_ + oh * W_ + ow) = acc[co];
}

extern "C" void kernel_launch(void* const* d_in, const int* in_sizes, int n_in,
                              void* d_out, int out_size, void* d_ws, size_t ws_size,
                              hipStream_t stream)
{
    const float* x    = (const float*)d_in[0];
    const float* w    = (const float*)d_in[1];
    const float* bias = (const float*)d_in[2];
    float* out        = (float*)d_out;

    dim3 grid(W_ / TW, H_ / TH, B_ * 2);   // (7, 14, 16) = 1568 blocks
    dim3 block(256);
    conv_quant_sum_kernel<<<grid, block, 0, stream>>>(x, w, bias, out);
}

// Round 12
// 83.366 us; speedup vs baseline: 1.0070x; 1.0070x over previous
//
#include <hip/hip_runtime.h>

// out[b,co,h,w] = sum_ci dq( conv3x3(x[b,ci], W[ci,co]) + b[ci,co] )
// Bit-exactness contract (verified R3 absmax==0, R4..R11 = 1.430511e-6):
//   per-pixel conv = sequential fma over k=(kh*3+kw) ascending, seeded from 0;
//   bias after as plain f32 add; t = y * (float)(15/9); rintf (half-even);
//   dequant+sum: fma(q, 0.6f, acc), ci ascending. v_pk_fma_f32 is IEEE per
//   32-bit half -> identical bits per pixel.
// R12: amortize the per-ci weight-fetch drain (SMEM s_load -> lgkmcnt(0),
// the structural stall no TLP lever fixed in R7-R11) over 2x work/wave:
// thread = 2 cols x 2 rows = 4 px; two output rows share one weight fetch
// and 4 staged x-rows. Tile 16x16, COG=4, grid 784. LDS stride 22 -> ty
// stride 44 mod 32 = 12 -> 8 distinct bank-pair offsets, conflict-free.

typedef float v2f __attribute__((ext_vector_type(2)));

constexpr int B_    = 8;
constexpr int CIN   = 16;
constexpr int COUT  = 32;
constexpr int H_    = 112;
constexpr int W_    = 112;
constexpr int TW    = 16;            // tile width  (112 = 7*16)
constexpr int TH    = 16;            // tile height (112 = 7*16)
constexpr int HH_   = TH + 2;        // halo rows 18
constexpr int LDSW  = 22;            // even (b64) + conflict-free ty stride
constexpr int COG   = 4;             // co per wave

__global__ __launch_bounds__(256, 4)
void conv_quant_sum_kernel(const float* __restrict__ x,
                           const float* __restrict__ w,
                           const float* __restrict__ bias,
                           float* __restrict__ out)
{
#pragma clang fp contract(off)
    const float QS = (float)(15.0 / 9.0);   // 1.66666663f
    const float DQ = 0.6f;                  // post-round dequant multiplier

    __shared__ float xs[CIN][HH_][LDSW];    // 16*18*22*4 = 25.3 KB

    const int t    = threadIdx.x;
    const int lane = t & 63;
    const int tx   = lane & 7;              // pair col: pixels 2tx, 2tx+1
    const int ty2  = lane >> 3;             // row-pair 0..7 -> rows 2ty2, 2ty2+1
    const int wid  = __builtin_amdgcn_readfirstlane(t >> 6);

    const int tile_x = blockIdx.x * TW;
    const int tile_y = blockIdx.y * TH;
    const int b      = blockIdx.z >> 1;
    const int cog    = (blockIdx.z & 1) * 16 + wid * COG;   // 0..28 step 4

    // ---- stage x halo (18 rows x 20 loaded cols per ci; cols 20-21 pad,
    //      never read). Two slots/thread, bounds computed once, 16
    //      independent ci-strided loads per slot (latency-batched). ----
    const float* xb = x + (size_t)b * CIN * H_ * W_;
    {
        const int sr0 = t / 20,         sc0 = t - sr0 * 20;          // t<256 -> sr0<13
        const int i1  = t + 256;
        const int sr1 = i1 / 20,        sc1 = i1 - sr1 * 20;         // valid if t<104
        const bool a1 = (sr1 < HH_);
        const int gh0 = tile_y + sr0 - 1, gw0 = tile_x + sc0 - 1;
        const int gh1 = tile_y + sr1 - 1, gw1 = tile_x + sc1 - 1;
        const bool in0 = ((unsigned)gh0 < (unsigned)H_) && ((unsigned)gw0 < (unsigned)W_);
        const bool in1 = a1 && ((unsigned)gh1 < (unsigned)H_) && ((unsigned)gw1 < (unsigned)W_);
        const float* sp0 = in0 ? (xb + gh0 * W_ + gw0) : xb;
        const float* sp1 = in1 ? (xb + gh1 * W_ + gw1) : xb;
        float v0[CIN], v1[CIN];
#pragma unroll
        for (int ci = 0; ci < CIN; ++ci) { v0[ci] = sp0[ci * (H_ * W_)];
                                           v1[ci] = sp1[ci * (H_ * W_)]; }
#pragma unroll
        for (int ci = 0; ci < CIN; ++ci) { v0[ci] = in0 ? v0[ci] : 0.0f;
                                           v1[ci] = in1 ? v1[ci] : 0.0f; }
#pragma unroll
        for (int ci = 0; ci < CIN; ++ci) xs[ci][sr0][sc0] = v0[ci];
        if (a1) {
#pragma unroll
            for (int ci = 0; ci < CIN; ++ci) xs[ci][sr1][sc1] = v1[ci];
        }
    }
    __syncthreads();

    v2f acc[COG][2];
#pragma unroll
    for (int co = 0; co < COG; ++co) {
        acc[co][0] = v2f{0.0f, 0.0f};
        acc[co][1] = v2f{0.0f, 0.0f};
    }

    for (int ci = 0; ci < CIN; ++ci) {
        // 4 halo rows 2ty2..2ty2+3 feed output rows 2ty2, 2ty2+1
        v2f xw[4][3];
#pragma unroll
        for (int r = 0; r < 4; ++r) {
            const float* row = &xs[ci][2 * ty2 + r][2 * tx];
            v2f p0 = *reinterpret_cast<const v2f*>(row);      // cols 2tx,2tx+1
            v2f p1 = *reinterpret_cast<const v2f*>(row + 2);  // cols 2tx+2,+3
            xw[r][0] = p0;
            xw[r][1] = v2f{p0.y, p1.x};
            xw[r][2] = p1;
        }

        const float* wc = w + (ci * COUT + cog) * 9;   // wave-uniform scalar
        const float* bc = bias + ci * COUT + cog;
#pragma unroll
        for (int co = 0; co < COG; ++co) {
            v2f s0 = v2f{0.0f, 0.0f};                  // out row 2ty2
            v2f s1 = v2f{0.0f, 0.0f};                  // out row 2ty2+1
#pragma unroll
            for (int k = 0; k < 9; ++k) {              // k ascending per pixel
                float wv = wc[co * 9 + k];
                v2f wvv = v2f{wv, wv};
                s0 = __builtin_elementwise_fma(xw[k / 3][k % 3],     wvv, s0);
                s1 = __builtin_elementwise_fma(xw[k / 3 + 1][k % 3], wvv, s1);
            }
            float bv = bc[co];
            v2f bvv = v2f{bv, bv};
            v2f y0 = s0 + bvv, y1 = s1 + bvv;          // bias: pk_add
            v2f t0 = y0 * v2f{QS, QS}, t1 = y1 * v2f{QS, QS};
            v2f q0, q1;
            q0.x = rintf(t0.x); q0.y = rintf(t0.y);    // v_rndne_f32 half-even
            q1.x = rintf(t1.x); q1.y = rintf(t1.y);
            acc[co][0] = __builtin_elementwise_fma(q0, v2f{DQ, DQ}, acc[co][0]);
            acc[co][1] = __builtin_elementwise_fma(q1, v2f{DQ, DQ}, acc[co][1]);
        }
    }

    // ---- store: 2 rows x 2 cols per thread, b64 each ----
    float* ob = out + ((size_t)b * COUT + cog) * H_ * W_;
    const int oh = tile_y + 2 * ty2;
    const int ow = tile_x + 2 * tx;
#pragma unroll
    for (int co = 0; co < COG; ++co) {
        *reinterpret_cast<v2f*>(ob + co * H_ * W_ + oh * W_ + ow)        = acc[co][0];
        *reinterpret_cast<v2f*>(ob + co * H_ * W_ + (oh + 1) * W_ + ow)  = acc[co][1];
    }
}

extern "C" void kernel_launch(void* const* d_in, const int* in_sizes, int n_in,
                              void* d_out, int out_size, void* d_ws, size_t ws_size,
                              hipStream_t stream)
{
    const float* x    = (const float*)d_in[0];
    const float* w    = (const float*)d_in[1];
    const float* bias = (const float*)d_in[2];
    float* out        = (float*)d_out;

    dim3 grid(W_ / TW, H_ / TH, B_ * 2);   // (7, 7, 16) = 784 blocks
    dim3 block(256);
    conv_quant_sum_kernel<<<grid, block, 0, stream>>>(x, w, bias, out);
}